// Round 4
// baseline (313.849 us; speedup 1.0000x reference)
//
#include <hip/hip_runtime.h>
#include <hip/hip_bf16.h>

#define S_DIM 8192
#define N_HALF 4096

typedef __attribute__((ext_vector_type(8))) short short8v;
typedef __attribute__((ext_vector_type(16))) float f32x16;
typedef __attribute__((ext_vector_type(2))) float f32x2;

__device__ inline unsigned short f32_to_bf16(float f) {
    unsigned int b = __builtin_bit_cast(unsigned int, f);
    unsigned int lsb = (b >> 16) & 1u;
    b += 0x7fffu + lsb;
    return (unsigned short)(b >> 16);
}
__device__ inline unsigned int fkey(float f) {
    unsigned int b = __builtin_bit_cast(unsigned int, f);
    return (b & 0x80000000u) ? ~b : (b | 0x80000000u);
}
__device__ inline float fkey_inv(unsigned int k) {
    unsigned int b = (k & 0x80000000u) ? (k & 0x7FFFFFFFu) : ~k;
    return __builtin_bit_cast(float, b);
}

// ---- fp8 e4m3fn helpers (all values positive) ----
__device__ inline unsigned int f32_to_fp8_scalar(float f) {
#if __has_builtin(__builtin_amdgcn_cvt_pk_fp8_f32)
    return (unsigned int)__builtin_amdgcn_cvt_pk_fp8_f32(f, f, 0, false) & 0xFFu;
#else
    if (f < 0.015625f) return (unsigned int)__float2int_rn(f * 512.0f);
    unsigned int b = __builtin_bit_cast(unsigned int, f);
    unsigned int r = b + 0x7FFFFu + ((b >> 20) & 1u);
    return (r >> 20) - 960u;
#endif
}
__device__ inline unsigned int pack_fp8x4(float a, float b, float c, float d) {
#if __has_builtin(__builtin_amdgcn_cvt_pk_fp8_f32)
    int w = __builtin_amdgcn_cvt_pk_fp8_f32(a, b, 0, false);
    w = __builtin_amdgcn_cvt_pk_fp8_f32(c, d, w, true);
    return (unsigned int)w;
#else
    return f32_to_fp8_scalar(a) | (f32_to_fp8_scalar(b) << 8) |
           (f32_to_fp8_scalar(c) << 16) | (f32_to_fp8_scalar(d) << 24);
#endif
}
#if !__has_builtin(__builtin_amdgcn_cvt_pk_f32_fp8)
__device__ inline float fp8_byte_to_f32(unsigned int u) {
    unsigned int e = (u >> 3) & 15u, m = u & 7u;
    if (e == 0) return (float)m * 0x1p-9f;
    return __builtin_bit_cast(float, ((e + 120u) << 23) | (m << 20));
}
#endif
__device__ inline void fp8x4_to_f32(unsigned int d, float* o) {
#if __has_builtin(__builtin_amdgcn_cvt_pk_f32_fp8)
    f32x2 lo = __builtin_amdgcn_cvt_pk_f32_fp8((int)d, false);
    f32x2 hi = __builtin_amdgcn_cvt_pk_f32_fp8((int)d, true);
    o[0] = lo[0]; o[1] = lo[1]; o[2] = hi[0]; o[3] = hi[1];
#else
    o[0] = fp8_byte_to_f32(d & 0xFFu);
    o[1] = fp8_byte_to_f32((d >> 8) & 0xFFu);
    o[2] = fp8_byte_to_f32((d >> 16) & 0xFFu);
    o[3] = fp8_byte_to_f32((d >> 24) & 0xFFu);
#endif
}

// triangle enumeration: id -> (bi <= bj)
__device__ inline void tri_map(int id, int& bi, int& bj) {
    int j = (int)((sqrtf(8.0f * (float)id + 1.0f) - 1.0f) * 0.5f);
    while ((j + 1) * (j + 2) / 2 <= id) ++j;
    while (j * (j + 1) / 2 > id) --j;
    bj = j;
    bi = id - j * (j + 1) / 2;
}

// one wave per row: L2-normalize; write fp32 (for loss) + bf16 fragment-major; init misc
// fragment-major granule(16B): idx16(row,chunk) = (row>>5)*512 + chunk*32 + (row&31)
__global__ __launch_bounds__(64) void normalize_kernel(const float* __restrict__ z,
                                                       float* __restrict__ zn,
                                                       unsigned int* __restrict__ znb,
                                                       float* __restrict__ acc0,
                                                       float* __restrict__ acc1,
                                                       unsigned int* __restrict__ minslot,
                                                       float* __restrict__ lossacc,
                                                       unsigned int* __restrict__ counter) {
    int row = blockIdx.x;
    int t = threadIdx.x;
    float2 val = ((const float2*)(z + (size_t)row * 128))[t];
    float ss = val.x * val.x + val.y * val.y;
    #pragma unroll
    for (int off = 32; off; off >>= 1) ss += __shfl_xor(ss, off);
    float inv = 1.0f / sqrtf(ss);
    float2 o; o.x = val.x * inv; o.y = val.y * inv;
    ((float2*)(zn + (size_t)row * 128))[t] = o;
    unsigned int p = (unsigned int)f32_to_bf16(o.x) | ((unsigned int)f32_to_bf16(o.y) << 16);
    // dword t of row -> chunk t>>2, dword-in-granule t&3
    znb[((row >> 5) * 512 + (t >> 2) * 32 + (row & 31)) * 4 + (t & 3)] = p;
    if (t == 0) {
        acc0[row] = 1.0f;   // x0 = 1/acc0 = 1
        acc1[row] = 0.0f;   // target of pass 1
        if (row == 0) { *minslot = 0xFFFFFFFFu; *lossacc = 0.0f; *counter = 0u; }
    }
}

// Triangle GEMM: block id -> (bi<=bj); computes C-tile (bi rows x bj cols) 128x128,
// 4 waves 2x2, MFMA 32x32x16. Fragment loads are 1KB-contiguous (fragment-major znb).
// Epilogue: K' = exp(10*min(cos,0.6)) fp8 (0 on true diagonal), swizzled LDS transpose,
// coalesced store at lower-triangle block (bj, bi).
__global__ __launch_bounds__(256, 4) void gemm_exp_mfma(const short* __restrict__ znb,
                                                        unsigned char* __restrict__ K8,
                                                        unsigned int* __restrict__ minslot) {
    __shared__ unsigned int Tl[128 * 32];
    __shared__ float wmins[4];
    int bi, bj;
    tri_map(blockIdx.x, bi, bj);
    const int t = threadIdx.x;
    const int lane = t & 63, wid = t >> 6;
    const int wm = wid >> 1, wn = wid & 1;
    const int cl = lane & 31, hi = lane >> 5;
    const int rowA = bi * 128 + wm * 64;
    const int rowB = bj * 128 + wn * 64;
    const short8v* Z = (const short8v*)znb;

    f32x16 acc[2][2];
    #pragma unroll
    for (int ti = 0; ti < 2; ++ti)
        #pragma unroll
        for (int tj = 0; tj < 2; ++tj)
            #pragma unroll
            for (int e = 0; e < 16; ++e) acc[ti][tj][e] = 0.0f;

    #pragma unroll
    for (int step = 0; step < 8; ++step) {
        const int chunk = step * 2 + hi;
        short8v af[2], bf[2];
        #pragma unroll
        for (int ti = 0; ti < 2; ++ti) {
            int r = rowA + ti * 32;   // 32-aligned
            af[ti] = Z[(r >> 5) * 512 + chunk * 32 + cl];
        }
        #pragma unroll
        for (int tj = 0; tj < 2; ++tj) {
            int r = rowB + tj * 32;
            bf[tj] = Z[(r >> 5) * 512 + chunk * 32 + cl];
        }
        #pragma unroll
        for (int ti = 0; ti < 2; ++ti)
            #pragma unroll
            for (int tj = 0; tj < 2; ++tj)
                acc[ti][tj] = __builtin_amdgcn_mfma_f32_32x32x16_bf16(af[ti], bf[tj], acc[ti][tj], 0, 0, 0);
    }

    // C layout: col = lane&31, row = (reg&3) + 8*(reg>>2) + 4*(lane>>5)
    float mn = 3.0e38f;
    #pragma unroll
    for (int ti = 0; ti < 2; ++ti)
        #pragma unroll
        for (int tj = 0; tj < 2; ++tj) {
            int colL = wn * 64 + tj * 32 + cl;
            int colG = bj * 128 + colL;
            int gswz = ((colL & 15) << 1) | ((colL >> 3) & 1);
            #pragma unroll
            for (int g = 0; g < 4; ++g) {
                int rowG = rowA + ti * 32 + 8 * g + 4 * hi;   // + k for element k
                float ev[4];
                #pragma unroll
                for (int k = 0; k < 4; ++k) {
                    float c = acc[ti][tj][g * 4 + k];
                    mn = fminf(mn, c);
                    float e = __expf(10.0f * fminf(c, 0.6f));
                    ev[k] = (rowG + k == colG) ? 0.0f : e;   // true diagonal stored as 0
                }
                unsigned int w = pack_fp8x4(ev[0], ev[1], ev[2], ev[3]);
                int r4b = wm * 16 + ti * 8 + 2 * g + hi;
                Tl[colL * 32 + (r4b ^ gswz)] = w;
            }
        }
    #pragma unroll
    for (int off = 32; off; off >>= 1) mn = fminf(mn, __shfl_xor(mn, off));
    if (lane == 0) wmins[wid] = mn;
    __syncthreads();
    if (t == 0) {
        float bmin = fminf(fminf(wmins[0], wmins[1]), fminf(wmins[2], wmins[3]));
        unsigned int key = fkey(bmin);
        if (key < *((volatile unsigned int*)minslot)) atomicMin(minslot, key);
    }

    // store transposed block at (bj, bi) -- lower triangle
    const size_t gbase = (size_t)(bj * 128) * S_DIM + (size_t)bi * 128;
    #pragma unroll
    for (int it = 0; it < 4; ++it) {
        int c = it * 32 + (t >> 3);
        int dq = (t & 7) * 4;
        int g2 = ((c & 15) << 1) | ((c >> 3) & 1);
        uint4 w;
        w.x = Tl[c * 32 + ((dq + 0) ^ g2)];
        w.y = Tl[c * 32 + ((dq + 1) ^ g2)];
        w.z = Tl[c * 32 + ((dq + 2) ^ g2)];
        w.w = Tl[c * 32 + ((dq + 3) ^ g2)];
        *(uint4*)(K8 + gbase + (size_t)c * S_DIM + dq * 4) = w;
    }
}

// Symmetric matvec pass: block id -> stored block (R=bj*128, C=bi*128), R>=C.
// x = 1/accPrev computed on the fly. Row pass: accCur[R+r] += sum_c K[r][c]*x[C+c]
// (+ kd*x[r] on diag). Col pass (off-diag only): accCur[C+c] += sum_r K[r][c]*x[R+r].
// Blocks 0..31 also zero accNext (used by the NEXT pass).
__global__ __launch_bounds__(256) void matvec_sym(const unsigned char* __restrict__ K8,
                                                  const float* __restrict__ accPrev,
                                                  float* __restrict__ accCur,
                                                  float* __restrict__ accNext,
                                                  const unsigned int* __restrict__ minslot) {
    __shared__ float xsr[128], xsc[128], csum4[4 * 128];
    const int id = blockIdx.x;
    const int t = threadIdx.x;
    if (id < 32) accNext[id * 256 + t] = 0.0f;

    int bi, bj;
    tri_map(id, bi, bj);
    const int Rb = bj * 128, Cb = bi * 128;
    const bool diag = (bi == bj);
    if (t < 128) xsr[t] = 1.0f / accPrev[Rb + t];
    else         xsc[t - 128] = 1.0f / accPrev[Cb + t - 128];
    __syncthreads();

    const float kd = diag ? __expf(10.0f * fkey_inv(*minslot)) : 0.0f;
    const int w = t >> 6, lane = t & 63, r2 = lane >> 5, d = lane & 31;
    const int rbase = w * 32;
    float ca0 = 0.0f, ca1 = 0.0f, ca2 = 0.0f, ca3 = 0.0f;
    const float4 xc = *(const float4*)&xsc[d * 4];

    #pragma unroll
    for (int j = 0; j < 16; ++j) {
        int rl = rbase + j * 2 + r2;
        unsigned int kw = *(const unsigned int*)(K8 + (size_t)(Rb + rl) * S_DIM + Cb + d * 4);
        float f[4];
        fp8x4_to_f32(kw, f);
        float xr = xsr[rl];
        float rd = f[0] * xc.x + f[1] * xc.y + f[2] * xc.z + f[3] * xc.w;
        #pragma unroll
        for (int off = 1; off <= 16; off <<= 1) rd += __shfl_xor(rd, off);
        if (diag) {
            if (d == 0) atomicAdd(&accCur[Rb + rl], rd + kd * xr);
        } else {
            if (d == 0) atomicAdd(&accCur[Rb + rl], rd);
            ca0 += f[0] * xr; ca1 += f[1] * xr; ca2 += f[2] * xr; ca3 += f[3] * xr;
        }
    }
    if (!diag) {
        ca0 += __shfl_xor(ca0, 32);
        ca1 += __shfl_xor(ca1, 32);
        ca2 += __shfl_xor(ca2, 32);
        ca3 += __shfl_xor(ca3, 32);
        if (lane < 32) {
            float4 v; v.x = ca0; v.y = ca1; v.z = ca2; v.w = ca3;
            *(float4*)&csum4[w * 128 + d * 4] = v;
        }
    }
    __syncthreads();
    if (!diag && t < 128) {
        float s = csum4[t] + csum4[128 + t] + csum4[256 + t] + csum4[384 + t];
        atomicAdd(&accCur[Cb + t], s);
    }
}

// fused loss: pair-dot + log-sum + finalize. log w11 = -log(acc11) (+10 scale), log w10 = -log(acc10)
__global__ __launch_bounds__(256) void loss_kernel(const float* __restrict__ zn,
                                                   const float* __restrict__ acc11,
                                                   const float* __restrict__ acc10,
                                                   float* __restrict__ lossacc,
                                                   unsigned int* __restrict__ counter,
                                                   float* __restrict__ out) {
    __shared__ float bs;
    int t = threadIdx.x, lane = t & 63, w = t >> 6;
    if (t == 0) bs = 0.0f;
    __syncthreads();
    int i = blockIdx.x * 4 + w;
    float2 p = ((const float2*)(zn + (size_t)i * 128))[lane];
    float2 q = ((const float2*)(zn + (size_t)(i + N_HALF) * 128))[lane];
    float d = p.x * q.x + p.y * q.y;
    float lg = 0.0f;
    if (t < 8) {
        int idx = blockIdx.x * 8 + t;
        lg = 10.0f - __logf(acc11[idx]) - __logf(acc10[idx]);
    }
    float val = 20.0f * (d - 1.0f) / 64.0f + lg;
    #pragma unroll
    for (int off = 32; off; off >>= 1) val += __shfl_xor(val, off);
    if (lane == 0) atomicAdd(&bs, val);
    __syncthreads();
    if (t == 0) {
        atomicAdd(lossacc, bs);
        __threadfence();
        unsigned int done = atomicAdd(counter, 1u);
        if (done == gridDim.x - 1) {
            __threadfence();
            out[0] = -(*lossacc) / (float)S_DIM;
        }
    }
}

extern "C" void kernel_launch(void* const* d_in, const int* in_sizes, int n_in,
                              void* d_out, int out_size, void* d_ws, size_t ws_size,
                              hipStream_t stream) {
    const float* z = (const float*)d_in[0];
    float* out = (float*)d_out;
    char* ws = (char*)d_ws;

    float* zn          = (float*)ws;                          // 4 MB fp32 normalized
    unsigned int* znb  = (unsigned int*)(ws + (4 << 20));     // 2 MB bf16 fragment-major
    float* buf0        = (float*)(ws + (6 << 20));            // 32 KB acc buffers x3
    float* buf1        = (float*)(ws + (6 << 20) + 65536);
    float* buf2        = (float*)(ws + (6 << 20) + 131072);
    unsigned int* mins = (unsigned int*)(ws + (6 << 20) + 196608);
    float* lossacc     = (float*)(ws + (6 << 20) + 196608 + 64);
    unsigned int* cnt  = (unsigned int*)(ws + (6 << 20) + 196608 + 128);
    unsigned char* K8  = (unsigned char*)(ws + (8 << 20));    // 64 MB fp8 K' (lower triangle)

    float* bufs[3] = {buf0, buf1, buf2};
    const int NTRI = 64 * 65 / 2;   // 2080

    normalize_kernel<<<S_DIM, 64, 0, stream>>>(z, zn, znb, buf0, buf1, mins, lossacc, cnt);
    gemm_exp_mfma<<<NTRI, 256, 0, stream>>>((const short*)znb, K8, mins);

    // pass p: reads bufs[(p-1)%3], accumulates bufs[p%3], zeros bufs[(p+1)%3]
    for (int p = 1; p <= 11; ++p) {
        matvec_sym<<<NTRI, 256, 0, stream>>>(K8, bufs[(p - 1) % 3], bufs[p % 3],
                                             bufs[(p + 1) % 3], mins);
    }
    // acc10 = bufs[10%3] = buf1, acc11 = bufs[11%3] = buf2
    loss_kernel<<<N_HALF / 4, 256, 0, stream>>>(zn, buf2, buf1, lossacc, cnt, out);
}